// Round 8
// baseline (307.281 us; speedup 1.0000x reference)
//
#include <hip/hip_runtime.h>
#include <stdint.h>

#define T_SEQ 2048
#define NH 16
#define HD 64
#define DM 1024
#define BB 4
#define MROWS (BB * T_SEQ)   // 8192

// Q projection is pre-scaled by 1/sqrt(HD) * log2(e) so attention scores are
// already in the log2 domain: P = exp2(s - m), alpha = exp2(m_old - m_new).
#define QSCALE 0.18033688011112042f  // 0.125 * log2(e)

typedef __attribute__((ext_vector_type(8))) __bf16 bf16x8;
typedef __attribute__((ext_vector_type(8))) unsigned short u16x8;
typedef __attribute__((ext_vector_type(4))) unsigned short u16x4;
typedef __attribute__((ext_vector_type(4))) float f32x4;

// Native cast -> compiler emits v_cvt_pk_bf16_f32 (RNE, pairs fuse).
__device__ __forceinline__ unsigned short f2bf(float f) {
  return __builtin_bit_cast(unsigned short, (__bf16)f);
}

__device__ __forceinline__ bf16x8 ld8_f32(const float* __restrict__ p) {
  f32x4 a = *(const f32x4*)p;
  f32x4 b = *(const f32x4*)(p + 4);
  u16x8 u;
#pragma unroll
  for (int i = 0; i < 4; ++i) {
    u[i]     = f2bf(a[i]);
    u[i + 4] = f2bf(b[i]);
  }
  return __builtin_bit_cast(bf16x8, u);
}

__device__ __forceinline__ bf16x8 ld8_bf(const unsigned short* p) {
  return __builtin_bit_cast(bf16x8, *(const u16x8*)p);
}

// 8-aligned LDS read as two b64s (stride-68 layouts are not 16B-aligned)
__device__ __forceinline__ bf16x8 ld8_lds(const unsigned short* p) {
  u16x4 a = *(const u16x4*)p;
  u16x4 b = *(const u16x4*)(p + 4);
  return __builtin_bit_cast(bf16x8,
      __builtin_shufflevector(a, b, 0, 1, 2, 3, 4, 5, 6, 7));
}

__device__ __forceinline__ u16x4 lo4(u16x8 v) {
  return __builtin_shufflevector(v, v, 0, 1, 2, 3);
}
__device__ __forceinline__ u16x4 hi4(u16x8 v) {
  return __builtin_shufflevector(v, v, 4, 5, 6, 7);
}

__device__ __forceinline__ void gload_lds16(const unsigned short* g,
                                            unsigned short* l) {
  __builtin_amdgcn_global_load_lds(
      (const __attribute__((address_space(1))) unsigned int*)g,
      (__attribute__((address_space(3))) unsigned int*)l, 16, 0, 0);
}

// ---------------------------------------------------------------------------
// fp32 -> bf16 elementwise (8 elems/thread).
// ---------------------------------------------------------------------------
__global__ __launch_bounds__(256) void conv_f32_bf16(
    const float* __restrict__ src, unsigned short* __restrict__ dst, int n8) {
  const int i = blockIdx.x * 256 + threadIdx.x;
  if (i < n8)
    *(u16x8*)(dst + (size_t)i * 8) =
        __builtin_bit_cast(u16x8, ld8_f32(src + (size_t)i * 8));
}

// Fused stage-1 conversion — 4 weights + x_kv in ONE dispatch.
__global__ __launch_bounds__(256) void conv_stage1(
    const float* __restrict__ Wk, const float* __restrict__ Wv,
    const float* __restrict__ Wq, const float* __restrict__ Wo,
    const float* __restrict__ xkv, unsigned short* __restrict__ Wkb012,
    unsigned short* __restrict__ Wob, unsigned short* __restrict__ Sx) {
  const int bid = blockIdx.x;
  const int WSEG = (DM * DM / 8) / 256;  // 512 blocks per weight
  if (bid < 4 * WSEG) {
    const int w = bid >> 9;
    const float* src = (w == 0) ? Wk : (w == 1) ? Wv : (w == 2) ? Wq : Wo;
    unsigned short* dst = (w < 3) ? Wkb012 + (size_t)w * DM * DM : Wob;
    const int i = (bid & (WSEG - 1)) * 256 + threadIdx.x;
    *(u16x8*)(dst + (size_t)i * 8) =
        __builtin_bit_cast(u16x8, ld8_f32(src + (size_t)i * 8));
  } else {
    const int i = (bid - 4 * WSEG) * 256 + threadIdx.x;
    *(u16x8*)(Sx + (size_t)i * 8) =
        __builtin_bit_cast(u16x8, ld8_f32(xkv + (size_t)i * 8));
  }
}

// ---------------------------------------------------------------------------
// R8: 256-row-tile bf16 GEMM, C = A[M,K] @ B[N,K]^T. BM=256, BN=256 or 128,
// 512 threads (8 waves), 1 block/CU. Same verified 2-phase dbuf gload_lds
// schedule as R6 (parameter change only; T3 recipe: param changes inherit
// the template's verification). Catalog reference: 256²+2ph @ K=1024 =
// 655-682 TF (m248/m230) vs our 128²'s ~430. Mechanism: 64 MFMA per
// 12 ds_read_b128 per wave per K-step (vs 32:16) + 2x barrier amortization.
// BN=256: waves 2Mx4N (wave out 128x64, acc 128 VGPR). BN=128: 4Mx2N
// (64x64, acc 64 VGPR). LDS 128KB / 96KB. launch_bounds(512,2) -> 256 VGPR.
// MODE 1: f32 row-major (O). MODE 3: fused K+V, N=2048 (n0<DM -> K row-major
// stride DM; else Vt[b][h][d][t]); block-uniform since BN=256 divides DM.
// MODE 4: bf16 row-major * QSCALE (Q).
// ---------------------------------------------------------------------------
template <int BN, int MODE>
__global__ __launch_bounds__(512, 2) void gemm256(
    const unsigned short* __restrict__ A, const unsigned short* __restrict__ B,
    void* __restrict__ Cv, void* __restrict__ Cv2, int M, int N, int K) {
  constexpr int BM = 256;
  constexpr int WM = (BN == 256) ? 2 : 4;   // waves tiling M
  constexpr int WN = 8 / WM;                // waves tiling N
  constexpr int RM = (BM / WM) / 16;        // 8 (BN=256) or 4
  constexpr int RN = (BN / WN) / 16;        // 4

  __shared__ __align__(16) unsigned short As[2][2][BM * 32];
  __shared__ __align__(16) unsigned short Bs[2][2][BN * 32];

  const int t = threadIdx.x;
  const int lane = t & 63, wave = t >> 6;
  const int lin = (int)(blockIdx.x + gridDim.x * blockIdx.y);  // 0..255
  const int nx = N / BN;
  const int mpx = (M / BM) >> 3;            // m-panels per XCD
  const int xcd = lin & 7, slot = lin >> 3;
  const int m0 = (xcd * mpx + slot / nx) * BM;
  const int n0 = (slot % nx) * BN;

  // staging: thread t covers row srow (+128 for second half), 8 cols.
  const int srow = t >> 2;                  // 0..127
  const int scol = (t & 3) * 8;
  const unsigned short* ga0 = A + (size_t)(m0 + srow) * K + scol;
  const unsigned short* ga1 = A + (size_t)(m0 + 128 + srow) * K + scol;
  const unsigned short* gb0 = B + (size_t)(n0 + srow) * K + scol;
  const unsigned short* gb1 = B + (size_t)(n0 + 128 + srow) * K + scol;

  // wave -> (wm, wn) and output offsets
  const int wm = (BN == 256) ? (wave >> 2) : (wave >> 1);
  const int wn = (BN == 256) ? (wave & 3) : (wave & 1);
  const int mw = wm * (BM / WM);
  const int nw = wn * (BN / WN);
  const int fr = lane & 15, fq = (lane >> 4) * 8;

  f32x4 acc[RM][RN];
#pragma unroll
  for (int i = 0; i < RM; ++i)
#pragma unroll
    for (int j = 0; j < RN; ++j) acc[i][j] = (f32x4){0.f, 0.f, 0.f, 0.f};

  // gload_lds: wave-uniform LDS base + lane*16B fills rows wave*16..+15 of a
  // [rows][32] u16 plane; per-lane global src matches (row = wave*16+(l>>2)).
  auto stage = [&](int buf, int k0) {
#pragma unroll
    for (int ks = 0; ks < 2; ++ks) {
      const int kk = k0 + ks * 32;
      gload_lds16(ga0 + kk, &As[buf][ks][(wave * 16) * 32]);
      gload_lds16(ga1 + kk, &As[buf][ks][(128 + wave * 16) * 32]);
      gload_lds16(gb0 + kk, &Bs[buf][ks][(wave * 16) * 32]);
      if constexpr (BN == 256)
        gload_lds16(gb1 + kk, &Bs[buf][ks][(128 + wave * 16) * 32]);
    }
  };

  stage(0, 0);
  __syncthreads();

  const int NT = K >> 6;   // 16
  int cur = 0;
  for (int kt = 0; kt < NT; ++kt) {
    if (kt + 1 < NT) stage(cur ^ 1, (kt + 1) << 6);  // overlaps compute
#pragma unroll
    for (int ks = 0; ks < 2; ++ks) {
      bf16x8 af[RM], bfr[RN];
#pragma unroll
      for (int i = 0; i < RM; ++i)
        af[i] = ld8_bf(&As[cur][ks][(mw + i * 16 + fr) * 32 + fq]);
#pragma unroll
      for (int j = 0; j < RN; ++j)
        bfr[j] = ld8_bf(&Bs[cur][ks][(nw + j * 16 + fr) * 32 + fq]);
#pragma unroll
      for (int i = 0; i < RM; ++i)
#pragma unroll
        for (int j = 0; j < RN; ++j)
          acc[i][j] = __builtin_amdgcn_mfma_f32_16x16x32_bf16(
              af[i], bfr[j], acc[i][j], 0, 0, 0);
    }
    __syncthreads();  // drains vmcnt(0): next buf ready; cur safe to overwrite
    cur ^= 1;
  }

  const int orow = (lane >> 4) * 4, ocol = lane & 15;
  const bool kv_lo = (MODE == 3) && (n0 < DM);  // block-uniform (BN=256 | DM)
#pragma unroll
  for (int i = 0; i < RM; ++i)
#pragma unroll
    for (int j = 0; j < RN; ++j) {
      const int mb = m0 + mw + i * 16 + orow;
      const int n = n0 + nw + j * 16 + ocol;
      if constexpr (MODE == 3) {
        if (kv_lo) {  // K path: bf16 row-major, stride DM
#pragma unroll
          for (int r = 0; r < 4; ++r)
            ((unsigned short*)Cv)[(size_t)(mb + r) * DM + n] =
                f2bf(acc[i][j][r]);
        } else {      // V path: Vt[b][h][d][t]; 4 r values = consecutive t
          const int nv = n - DM;
          u16x4 pk;
#pragma unroll
          for (int r = 0; r < 4; ++r) pk[r] = f2bf(acc[i][j][r]);
          unsigned short* dst = (unsigned short*)Cv2 +
              ((size_t)((mb >> 11) * NH + (nv >> 6)) * HD + (nv & 63)) *
                  T_SEQ +
              (mb & 2047);
          *(u16x4*)dst = pk;
        }
      } else {
#pragma unroll
        for (int r = 0; r < 4; ++r) {
          const size_t idx = (size_t)(mb + r) * N + n;
          float v = acc[i][j][r];
          if constexpr (MODE == 4) v *= QSCALE;
          if constexpr (MODE == 1)
            ((float*)Cv)[idx] = v;
          else
            ((unsigned short*)Cv)[idx] = f2bf(v);
        }
      }
    }
}

// ---------------------------------------------------------------------------
// MFMA flash attention v2 (causal) — unchanged from R7 (89 µs, passed).
// Paired q-tiles {15-pi, pi}; S^T = K @ Q^T; scores pre-scaled to log2
// domain; defer-max (THR=8); alpha/l via width-16 shuffles; K/V LDS
// double-buffer, 1 barrier/tile.
// ---------------------------------------------------------------------------
#define ASTR 68

__global__ __launch_bounds__(256, 2) void attn_flash2(
    const unsigned short* Qw, const unsigned short* __restrict__ Kw,
    const unsigned short* __restrict__ Vt, unsigned short* Ow) {
  __shared__ __align__(16) unsigned short k_lds[2][64][ASTR];
  __shared__ __align__(16) unsigned short vt_lds[2][64][ASTR];
  __shared__ __align__(16) unsigned short p_lds[4][32][ASTR];

  const int tid = threadIdx.x, lane = tid & 63, wave = tid >> 6;
  const int c16 = lane & 15, quad = lane >> 4;
  const int b = blockIdx.z, h = blockIdx.y;
  const int pi = blockIdx.x;            // pair index 0..7
  const int qb0A = (15 - pi) * 128;     // heavy
  const int qb0B = pi * 128;            // light
  const size_t rkbase = (size_t)b * T_SEQ * DM + (size_t)h * HD;
  const size_t vtbase = (size_t)(b * NH + h) * HD * T_SEQ;

  const int q_loA = qb0A + wave * 32;
  const int q_loB = qb0B + wave * 32;

  bf16x8 qfA[2][2], qfB[2][2];
#pragma unroll
  for (int nf = 0; nf < 2; ++nf) {
    const unsigned short* qpA =
        Qw + rkbase + (size_t)(q_loA + nf * 16 + c16) * DM + quad * 8;
    qfA[nf][0] = ld8_bf(qpA);
    qfA[nf][1] = ld8_bf(qpA + 32);
    const unsigned short* qpB =
        Qw + rkbase + (size_t)(q_loB + nf * 16 + c16) * DM + quad * 8;
    qfB[nf][0] = ld8_bf(qpB);
    qfB[nf][1] = ld8_bf(qpB + 32);
  }

  f32x4 oA[2][4], oB[2][4];
#pragma unroll
  for (int nf = 0; nf < 2; ++nf)
#pragma unroll
    for (int j = 0; j < 4; ++j) {
      oA[nf][j] = (f32x4){0.f, 0.f, 0.f, 0.f};
      oB[nf][j] = (f32x4){0.f, 0.f, 0.f, 0.f};
    }
  float mA[2] = {-3.0e38f, -3.0e38f}, lA[2] = {0.f, 0.f};
  float mB[2] = {-3.0e38f, -3.0e38f}, lB[2] = {0.f, 0.f};

  const int srow = tid >> 2;
  const int scol = (tid & 3) * 16;
  const int ntiles = (qb0A + 191) >> 6;
  const int ntA_w = (q_loA + 95) >> 6;
  const int ntB_w = (q_loB + 95) >> 6;

  const unsigned short* kp0 = Kw + rkbase + (size_t)srow * DM + scol;
  const unsigned short* vp0 = Vt + vtbase + (size_t)srow * T_SEQ + scol;

  auto subtile = [&](const bf16x8 (&qf)[2][2], f32x4 (&o)[2][4],
                     float (&m_r)[2], float (&l_r)[2], const int q_lo,
                     const int kb0, const int bi) {
    f32x4 s[4][2];
    __builtin_amdgcn_s_setprio(1);
#pragma unroll
    for (int mf = 0; mf < 4; ++mf) {
      const unsigned short* kr = &k_lds[bi][mf * 16 + c16][quad * 8];
      const bf16x8 k0 = ld8_lds(kr);
      const bf16x8 k1 = ld8_lds(kr + 32);
#pragma unroll
      for (int nf = 0; nf < 2; ++nf) {
        f32x4 a = {0.f, 0.f, 0.f, 0.f};
        a = __builtin_amdgcn_mfma_f32_16x16x32_bf16(k0, qf[nf][0], a, 0, 0, 0);
        a = __builtin_amdgcn_mfma_f32_16x16x32_bf16(k1, qf[nf][1], a, 0, 0, 0);
        s[mf][nf] = a;
      }
    }
    __builtin_amdgcn_s_setprio(0);
    if (kb0 + 63 > q_lo) {
#pragma unroll
      for (int mf = 0; mf < 4; ++mf) {
        const int key0 = kb0 + mf * 16 + quad * 4;
#pragma unroll
        for (int nf = 0; nf < 2; ++nf) {
          const int qg = q_lo + nf * 16 + c16;
#pragma unroll
          for (int r = 0; r < 4; ++r)
            if (key0 + r > qg) s[mf][nf][r] = -3.0e38f;
        }
      }
    }

#pragma unroll
    for (int nf = 0; nf < 2; ++nf) {
      float mx = -3.0e38f;
#pragma unroll
      for (int mf = 0; mf < 4; ++mf)
#pragma unroll
        for (int r = 0; r < 4; ++r) mx = fmaxf(mx, s[mf][nf][r]);
      mx = fmaxf(mx, __shfl_xor(mx, 16, 64));
      mx = fmaxf(mx, __shfl_xor(mx, 32, 64));
      if (!__all(mx - m_r[nf] <= 8.0f)) {
        const float m_new = fmaxf(m_r[nf], mx);
        const float al = exp2f(m_r[nf] - m_new);
        m_r[nf] = m_new;
        l_r[nf] *= al;
        float alr[4];
#pragma unroll
        for (int r = 0; r < 4; ++r) alr[r] = __shfl(al, quad * 4 + r, 16);
#pragma unroll
        for (int j = 0; j < 4; ++j)
#pragma unroll
          for (int r = 0; r < 4; ++r) o[nf][j][r] *= alr[r];
      }
      float ps = 0.f;
#pragma unroll
      for (int mf = 0; mf < 4; ++mf) {
        u16x4 pk;
#pragma unroll
        for (int r = 0; r < 4; ++r) {
          const float e = exp2f(s[mf][nf][r] - m_r[nf]);
          ps += e;
          pk[r] = f2bf(e);
        }
        *(u16x4*)&p_lds[wave][nf * 16 + c16][mf * 16 + quad * 4] = pk;
      }
      ps += __shfl_xor(ps, 16, 64);
      ps += __shfl_xor(ps, 32, 64);
      l_r[nf] += ps;
    }
    __threadfence_block();

    bf16x8 pf[2][2];
#pragma unroll
    for (int nf = 0; nf < 2; ++nf) {
      const unsigned short* pw = &p_lds[wave][nf * 16 + c16][quad * 8];
      pf[nf][0] = ld8_lds(pw);
      pf[nf][1] = ld8_lds(pw + 32);
    }
    __builtin_amdgcn_s_setprio(1);
#pragma unroll
    for (int j = 0; j < 4; ++j) {
      const unsigned short* vr = &vt_lds[bi][j * 16 + c16][quad * 8];
      const bf16x8 v0 = ld8_lds(vr);
      const bf16x8 v1 = ld8_lds(vr + 32);
#pragma unroll
      for (int nf = 0; nf < 2; ++nf) {
        o[nf][j] = __builtin_amdgcn_mfma_f32_16x16x32_bf16(pf[nf][0], v0,
                                                           o[nf][j], 0, 0, 0);
        o[nf][j] = __builtin_amdgcn_mfma_f32_16x16x32_bf16(pf[nf][1], v1,
                                                           o[nf][j], 0, 0, 0);
      }
    }
    __builtin_amdgcn_s_setprio(0);
  };

  {
    u16x8 ka = *(const u16x8*)kp0;
    u16x8 kc = *(const u16x8*)(kp0 + 8);
    u16x8 va = *(const u16x8*)vp0;
    u16x8 vc = *(const u16x8*)(vp0 + 8);
    *(u16x4*)&k_lds[0][srow][scol]       = lo4(ka);
    *(u16x4*)&k_lds[0][srow][scol + 4]   = hi4(ka);
    *(u16x4*)&k_lds[0][srow][scol + 8]   = lo4(kc);
    *(u16x4*)&k_lds[0][srow][scol + 12]  = hi4(kc);
    *(u16x4*)&vt_lds[0][srow][scol]      = lo4(va);
    *(u16x4*)&vt_lds[0][srow][scol + 4]  = hi4(va);
    *(u16x4*)&vt_lds[0][srow][scol + 8]  = lo4(vc);
    *(u16x4*)&vt_lds[0][srow][scol + 12] = hi4(vc);
  }
  __syncthreads();

  int cur = 0;
  for (int t = 0; t < ntiles; ++t) {
    const int kb0 = t * 64;
    const bool pf = (t + 1 < ntiles);
    u16x8 ka, kc, va, vc;
    if (pf) {
      const unsigned short* kp = kp0 + (size_t)(kb0 + 64) * DM;
      ka = *(const u16x8*)kp;
      kc = *(const u16x8*)(kp + 8);
      const unsigned short* vp = vp0 + (kb0 + 64);
      va = *(const u16x8*)vp;
      vc = *(const u16x8*)(vp + 8);
    }
    if (t < ntA_w) subtile(qfA, oA, mA, lA, q_loA, kb0, cur);
    if (t < ntB_w) subtile(qfB, oB, mB, lB, q_loB, kb0, cur);
    if (pf) {
      const int nb = cur ^ 1;
      *(u16x4*)&k_lds[nb][srow][scol]       = lo4(ka);
      *(u16x4*)&k_lds[nb][srow][scol + 4]   = hi4(ka);
      *(u16x4*)&k_lds[nb][srow][scol + 8]   = lo4(kc);
      *(u16x4*)&k_lds[nb][srow][scol + 12]  = hi4(kc);
      *(u16x4*)&vt_lds[nb][srow][scol]      = lo4(va);
      *(u16x4*)&vt_lds[nb][srow][scol + 4]  = hi4(va);
      *(u16x4*)&vt_lds[nb][srow][scol + 8]  = lo4(vc);
      *(u16x4*)&vt_lds[nb][srow][scol + 12] = hi4(vc);
      __syncthreads();
      cur = nb;
    }
  }

  auto epi = [&](f32x4 (&o)[2][4], float (&l_r)[2], const int q_lo) {
#pragma unroll
    for (int nf = 0; nf < 2; ++nf)
#pragma unroll
      for (int r = 0; r < 4; ++r) {
        const int qg = q_lo + nf * 16 + quad * 4 + r;
        const float inv = 1.0f / __shfl(l_r[nf], quad * 4 + r, 16);
        unsigned short* orow = Ow + rkbase + (size_t)qg * DM;
#pragma unroll
        for (int j = 0; j < 4; ++j)
          orow[j * 16 + c16] = f2bf(o[nf][j][r] * inv);
      }
  };
  epi(oA, lA, q_loA);
  epi(oB, lB, q_loB);
}

extern "C" void kernel_launch(void* const* d_in, const int* in_sizes, int n_in,
                              void* d_out, int out_size, void* d_ws, size_t ws_size,
                              hipStream_t stream) {
  const float* x_q  = (const float*)d_in[0];
  const float* x_kv = (const float*)d_in[1];
  const float* Wq   = (const float*)d_in[2];
  const float* Wk   = (const float*)d_in[3];
  const float* Wv   = (const float*)d_in[4];
  const float* Wo   = (const float*)d_in[5];
  float* out = (float*)d_out;

  // d_out doubles as early scratch; final GEMM reads only from ws.
  unsigned short* scr  = (unsigned short*)d_out;
  unsigned short* Sx   = scr;                          // x bf16 slot
  unsigned short* Wk_b = scr + (size_t)MROWS * DM;     // Wk|Wv|Wq contiguous
  unsigned short* Wv_b = Wk_b + (size_t)DM * DM;
  unsigned short* Wq_b = Wv_b + (size_t)DM * DM;

  unsigned short* qb   = (unsigned short*)d_ws;
  unsigned short* kb   = qb + (size_t)MROWS * DM;
  unsigned short* vtb  = kb + (size_t)MROWS * DM;      // Vt[b][h][d][t]
  unsigned short* Wo_b = vtb + (size_t)MROWS * DM;

  const int nW8 = DM * DM / 8;
  const int nX8 = MROWS * DM / 8;
  (void)Wv_b;

  // stage 1: all 4 weights + x_kv in one dispatch
  conv_stage1<<<4 * (nW8 / 256) + nX8 / 256, 256, 0, stream>>>(
      Wk, Wv, Wq, Wo, x_kv, Wk_b, Wo_b, Sx);

  // Fused K+V projection: B = [Wk_b ; Wv_b], N=2048, 256² tile, 256 blocks.
  gemm256<256, 3><<<dim3(2 * DM / 256, MROWS / 256), 512, 0, stream>>>(
      Sx, Wk_b, kb, vtb, MROWS, 2 * DM, DM);
  conv_f32_bf16<<<nX8 / 256, 256, 0, stream>>>(x_q, Sx, nX8);
  // Q projection (QSCALE folded), 256x128 tile, 256 blocks.
  gemm256<128, 4><<<dim3(DM / 128, MROWS / 256), 512, 0, stream>>>(
      Sx, Wq_b, qb, nullptr, MROWS, DM, DM);
  attn_flash2<<<dim3(8, NH, BB), 256, 0, stream>>>(qb, kb, vtb, qb);
  // Output projection, f32 out, 256x128 tile.
  gemm256<128, 1><<<dim3(DM / 128, MROWS / 256), 512, 0, stream>>>(
      qb, Wo_b, out, nullptr, MROWS, DM, DM);
}

// Round 9
// 298.814 us; speedup vs baseline: 1.0283x; 1.0283x over previous
//
#include <hip/hip_runtime.h>
#include <stdint.h>

#define T_SEQ 2048
#define NH 16
#define HD 64
#define DM 1024
#define BB 4
#define MROWS (BB * T_SEQ)   // 8192

// Q projection is pre-scaled by 1/sqrt(HD) * log2(e) so attention scores are
// already in the log2 domain: P = exp2(s - m), alpha = exp2(m_old - m_new).
#define QSCALE 0.18033688011112042f  // 0.125 * log2(e)

typedef __attribute__((ext_vector_type(8))) __bf16 bf16x8;
typedef __attribute__((ext_vector_type(8))) unsigned short u16x8;
typedef __attribute__((ext_vector_type(4))) unsigned short u16x4;
typedef __attribute__((ext_vector_type(4))) float f32x4;

// Native cast -> compiler emits v_cvt_pk_bf16_f32 (RNE, pairs fuse).
__device__ __forceinline__ unsigned short f2bf(float f) {
  return __builtin_bit_cast(unsigned short, (__bf16)f);
}

__device__ __forceinline__ bf16x8 ld8_f32(const float* __restrict__ p) {
  f32x4 a = *(const f32x4*)p;
  f32x4 b = *(const f32x4*)(p + 4);
  u16x8 u;
#pragma unroll
  for (int i = 0; i < 4; ++i) {
    u[i]     = f2bf(a[i]);
    u[i + 4] = f2bf(b[i]);
  }
  return __builtin_bit_cast(bf16x8, u);
}

__device__ __forceinline__ bf16x8 ld8_bf(const unsigned short* p) {
  return __builtin_bit_cast(bf16x8, *(const u16x8*)p);
}

// 8-aligned LDS read as two b64s (stride-68 layouts are not 16B-aligned)
__device__ __forceinline__ bf16x8 ld8_lds(const unsigned short* p) {
  u16x4 a = *(const u16x4*)p;
  u16x4 b = *(const u16x4*)(p + 4);
  return __builtin_bit_cast(bf16x8,
      __builtin_shufflevector(a, b, 0, 1, 2, 3, 4, 5, 6, 7));
}

__device__ __forceinline__ u16x4 lo4(u16x8 v) {
  return __builtin_shufflevector(v, v, 0, 1, 2, 3);
}
__device__ __forceinline__ u16x4 hi4(u16x8 v) {
  return __builtin_shufflevector(v, v, 4, 5, 6, 7);
}

__device__ __forceinline__ void gload_lds16(const unsigned short* g,
                                            unsigned short* l) {
  __builtin_amdgcn_global_load_lds(
      (const __attribute__((address_space(1))) unsigned int*)g,
      (__attribute__((address_space(3))) unsigned int*)l, 16, 0, 0);
}

// ---------------------------------------------------------------------------
// fp32 -> bf16 elementwise (8 elems/thread).
// ---------------------------------------------------------------------------
__global__ __launch_bounds__(256) void conv_f32_bf16(
    const float* __restrict__ src, unsigned short* __restrict__ dst, int n8) {
  const int i = blockIdx.x * 256 + threadIdx.x;
  if (i < n8)
    *(u16x8*)(dst + (size_t)i * 8) =
        __builtin_bit_cast(u16x8, ld8_f32(src + (size_t)i * 8));
}

// Fused stage-1 conversion — 4 weights + x_kv in ONE dispatch.
__global__ __launch_bounds__(256) void conv_stage1(
    const float* __restrict__ Wk, const float* __restrict__ Wv,
    const float* __restrict__ Wq, const float* __restrict__ Wo,
    const float* __restrict__ xkv, unsigned short* __restrict__ Wkb012,
    unsigned short* __restrict__ Wob, unsigned short* __restrict__ Sx) {
  const int bid = blockIdx.x;
  const int WSEG = (DM * DM / 8) / 256;  // 512 blocks per weight
  if (bid < 4 * WSEG) {
    const int w = bid >> 9;
    const float* src = (w == 0) ? Wk : (w == 1) ? Wv : (w == 2) ? Wq : Wo;
    unsigned short* dst = (w < 3) ? Wkb012 + (size_t)w * DM * DM : Wob;
    const int i = (bid & (WSEG - 1)) * 256 + threadIdx.x;
    *(u16x8*)(dst + (size_t)i * 8) =
        __builtin_bit_cast(u16x8, ld8_f32(src + (size_t)i * 8));
  } else {
    const int i = (bid - 4 * WSEG) * 256 + threadIdx.x;
    *(u16x8*)(Sx + (size_t)i * 8) =
        __builtin_bit_cast(u16x8, ld8_f32(xkv + (size_t)i * 8));
  }
}

// ---------------------------------------------------------------------------
// bf16 GEMM (R7 version restored — best measured pool; R8's 256² tile
// regressed: 1 block/CU left barrier drains and epilogue uncovered).
// C = A[M,K] @ B[N,K]^T. 128x128 tile, BK=64 (two BK=32 planes), 2-phase
// double-buffered gload_lds staging. XCD remap: XCD owns contiguous
// m-panels. MODE 0: bf16 row-major. MODE 1: f32 row-major.
// MODE 3: fused K+V (N=2048; n0<DM -> K row-major stride DM, else
// Vt[b][h][d][t]); block-uniform branch. MODE 4: bf16 row-major * QSCALE.
// ---------------------------------------------------------------------------
template <int MODE>
__global__ __launch_bounds__(256) void gemm128(
    const unsigned short* __restrict__ A, const unsigned short* __restrict__ B,
    void* __restrict__ Cv, void* __restrict__ Cv2, int M, int N, int K) {
  __shared__ __align__(16) unsigned short As[2][2][128 * 32];
  __shared__ __align__(16) unsigned short Bs[2][2][128 * 32];

  const int t = threadIdx.x;
  const int lane = t & 63, wave = t >> 6;
  const int lin = (int)(blockIdx.x + gridDim.x * blockIdx.y);
  const int nx = N >> 7;                       // n-tiles
  const int mpx = (M >> 7) >> 3;               // m-panels per XCD
  const int xcd = lin & 7, slot = lin >> 3;
  const int m0 = (xcd * mpx + slot / nx) * 128;
  const int n0 = (slot % nx) * 128;

  const int srow = t >> 2;
  const int scol = (t & 3) * 8;
  const unsigned short* ga0 = A + (size_t)(m0 + srow) * K + scol;
  const unsigned short* ga1 = A + (size_t)(m0 + 64 + srow) * K + scol;
  const unsigned short* gb0 = B + (size_t)(n0 + srow) * K + scol;
  const unsigned short* gb1 = B + (size_t)(n0 + 64 + srow) * K + scol;
  const int lo0 = (wave * 16) * 32, lo1 = (64 + wave * 16) * 32;

  const int mw = (wave >> 1) * 64, nw = (wave & 1) * 64;
  const int fr = lane & 15, fq = (lane >> 4) * 8;

  f32x4 acc[4][4];
#pragma unroll
  for (int i = 0; i < 4; ++i)
#pragma unroll
    for (int j = 0; j < 4; ++j) acc[i][j] = (f32x4){0.f, 0.f, 0.f, 0.f};

  auto stage = [&](int buf, int k0) {
    gload_lds16(ga0 + k0,      &As[buf][0][lo0]);
    gload_lds16(ga1 + k0,      &As[buf][0][lo1]);
    gload_lds16(gb0 + k0,      &Bs[buf][0][lo0]);
    gload_lds16(gb1 + k0,      &Bs[buf][0][lo1]);
    gload_lds16(ga0 + k0 + 32, &As[buf][1][lo0]);
    gload_lds16(ga1 + k0 + 32, &As[buf][1][lo1]);
    gload_lds16(gb0 + k0 + 32, &Bs[buf][1][lo0]);
    gload_lds16(gb1 + k0 + 32, &Bs[buf][1][lo1]);
  };

  // prologue: stage tile 0 (latency exposed once)
  stage(0, 0);
  __syncthreads();

  const int NT = K >> 6;   // 16
  int cur = 0;
  for (int kt = 0; kt < NT; ++kt) {
    if (kt + 1 < NT) stage(cur ^ 1, (kt + 1) << 6);  // overlaps compute below
#pragma unroll
    for (int ks = 0; ks < 2; ++ks) {
      bf16x8 af[4], bfr[4];
#pragma unroll
      for (int i = 0; i < 4; ++i)
        af[i] = ld8_bf(&As[cur][ks][(mw + i * 16 + fr) * 32 + fq]);
#pragma unroll
      for (int j = 0; j < 4; ++j)
        bfr[j] = ld8_bf(&Bs[cur][ks][(nw + j * 16 + fr) * 32 + fq]);
#pragma unroll
      for (int i = 0; i < 4; ++i)
#pragma unroll
        for (int j = 0; j < 4; ++j)
          acc[i][j] = __builtin_amdgcn_mfma_f32_16x16x32_bf16(
              af[i], bfr[j], acc[i][j], 0, 0, 0);
    }
    __syncthreads();  // drains vmcnt(0): next buf ready; cur safe to overwrite
    cur ^= 1;
  }

  const int orow = (lane >> 4) * 4, ocol = lane & 15;
  const bool kv_lo = (MODE == 3) && (n0 < DM);  // block-uniform
#pragma unroll
  for (int i = 0; i < 4; ++i)
#pragma unroll
    for (int j = 0; j < 4; ++j) {
      const int mb = m0 + mw + i * 16 + orow;
      const int n = n0 + nw + j * 16 + ocol;
      if constexpr (MODE == 3) {
        if (kv_lo) {  // K path: bf16 row-major, stride DM
#pragma unroll
          for (int r = 0; r < 4; ++r)
            ((unsigned short*)Cv)[(size_t)(mb + r) * DM + n] =
                f2bf(acc[i][j][r]);
        } else {      // V path: Vt[b][h][d][t]; 4 r values = consecutive t
          const int nv = n - DM;
          u16x4 pk;
#pragma unroll
          for (int r = 0; r < 4; ++r) pk[r] = f2bf(acc[i][j][r]);
          unsigned short* dst = (unsigned short*)Cv2 +
              ((size_t)((mb >> 11) * NH + (nv >> 6)) * HD + (nv & 63)) *
                  T_SEQ +
              (mb & 2047);
          *(u16x4*)dst = pk;
        }
      } else {
#pragma unroll
        for (int r = 0; r < 4; ++r) {
          const size_t idx = (size_t)(mb + r) * N + n;
          float v = acc[i][j][r];
          if constexpr (MODE == 4) v *= QSCALE;
          if constexpr (MODE == 1)
            ((float*)Cv)[idx] = v;
          else
            ((unsigned short*)Cv)[idx] = f2bf(v);
        }
      }
    }
}

// ---------------------------------------------------------------------------
// MFMA flash attention v2 (causal). R9: OCCUPANCY-DOUBLED layout.
// attn was latency-bound: per-pipe work sums to ~25 of 90 µs, rest is the
// serial QK->softmax->PV chain at only 2 waves/SIMD (grid 512 was the
// binding limit). Now: wave owns 16 q-rows (was 32); block = 4 waves = one
// 64-row HALF of heavy tile {15-pi} + matching half of light tile {pi}
// (pairing kept -> uniform work per block, dispatch-order robust).
// Grid 16x16x4 = 1024 blocks, ALL resident: 16 waves/CU (4/SIMD), 2x TLP.
// K/V single-buffered (R3 dbuf was neutral; occupancy is the lever),
// LDS 25.5KB. launch_bounds(256,4) -> 128-VGPR cap (state halved, ~100
// needed; WRITE_SIZE is the spill tripwire per R1).
// Scores arrive in log2 domain (QSCALE in Q GEMM); defer-max THR=8;
// alpha/l via width-16 shuffles. V pre-transposed (Vt[b][h][d][t]).
// ---------------------------------------------------------------------------
#define ASTR 68

__global__ __launch_bounds__(256, 4) void attn_flash2(
    const unsigned short* Qw, const unsigned short* __restrict__ Kw,
    const unsigned short* __restrict__ Vt, unsigned short* Ow) {
  __shared__ __align__(16) unsigned short k_lds[64][ASTR];
  __shared__ __align__(16) unsigned short vt_lds[64][ASTR];
  __shared__ __align__(16) unsigned short p_lds[4][16][ASTR];

  const int tid = threadIdx.x, lane = tid & 63, wave = tid >> 6;
  const int c16 = lane & 15, quad = lane >> 4;
  const int b = blockIdx.z, h = blockIdx.y;
  const int pi = blockIdx.x >> 1;        // pair index 0..7
  const int half = blockIdx.x & 1;       // which 64-row half
  const int qb0A = (15 - pi) * 128 + half * 64;  // heavy half
  const int qb0B = pi * 128 + half * 64;         // light half
  const size_t rkbase = (size_t)b * T_SEQ * DM + (size_t)h * HD;
  const size_t vtbase = (size_t)(b * NH + h) * HD * T_SEQ;

  const int q_loA = qb0A + wave * 16;
  const int q_loB = qb0B + wave * 16;

  // Q B-frags (resident): B[n=q][k=d], q = q_lo + c16, d = quad*8 + kf*32
  bf16x8 qfA[2], qfB[2];
  {
    const unsigned short* qpA =
        Qw + rkbase + (size_t)(q_loA + c16) * DM + quad * 8;
    qfA[0] = ld8_bf(qpA);
    qfA[1] = ld8_bf(qpA + 32);
    const unsigned short* qpB =
        Qw + rkbase + (size_t)(q_loB + c16) * DM + quad * 8;
    qfB[0] = ld8_bf(qpB);
    qfB[1] = ld8_bf(qpB + 32);
  }

  f32x4 oA[4], oB[4];
#pragma unroll
  for (int j = 0; j < 4; ++j) {
    oA[j] = (f32x4){0.f, 0.f, 0.f, 0.f};
    oB[j] = (f32x4){0.f, 0.f, 0.f, 0.f};
  }
  float mA = -3.0e38f, lAr = 0.f;
  float mB = -3.0e38f, lBr = 0.f;

  const int srow = tid >> 2;          // 0..63 (key idx for K, d idx for Vt)
  const int scol = (tid & 3) * 16;    // 0/16/32/48
  const int ntiles = (qb0A + 127) >> 6;   // heavy half bound covers light
  const int ntA_w = (q_loA + 79) >> 6;
  const int ntB_w = (q_loB + 79) >> 6;

  const unsigned short* kp0 = Kw + rkbase + (size_t)srow * DM + scol;
  const unsigned short* vp0 = Vt + vtbase + (size_t)srow * T_SEQ + scol;

  // per-subtile compute: S^T (64 keys x 16 q) -> online softmax -> PV
  auto subtile = [&](const bf16x8 (&qf)[2], f32x4 (&o)[4], float& m_r,
                     float& l_r, const int q_lo, const int kb0) {
    // ---- S^T = K @ Q^T : D[m=key][n=q] (scores already * QSCALE) ----
    f32x4 s[4];
    __builtin_amdgcn_s_setprio(1);
#pragma unroll
    for (int mf = 0; mf < 4; ++mf) {
      const unsigned short* kr = &k_lds[mf * 16 + c16][quad * 8];
      const bf16x8 k0 = ld8_lds(kr);
      const bf16x8 k1 = ld8_lds(kr + 32);
      f32x4 a = {0.f, 0.f, 0.f, 0.f};
      a = __builtin_amdgcn_mfma_f32_16x16x32_bf16(k0, qf[0], a, 0, 0, 0);
      a = __builtin_amdgcn_mfma_f32_16x16x32_bf16(k1, qf[1], a, 0, 0, 0);
      s[mf] = a;
    }
    __builtin_amdgcn_s_setprio(0);
    // causal mask: key = kb0+mf*16+quad*4+r, q = q_lo+c16 (pure select)
    if (kb0 + 63 > q_lo) {
      const int qg = q_lo + c16;
#pragma unroll
      for (int mf = 0; mf < 4; ++mf) {
        const int key0 = kb0 + mf * 16 + quad * 4;
#pragma unroll
        for (int r = 0; r < 4; ++r)
          if (key0 + r > qg) s[mf][r] = -3.0e38f;
      }
    }

    // ---- online softmax (per q = column): local + shfl 16,32 ----
    float mx = -3.0e38f;
#pragma unroll
    for (int mf = 0; mf < 4; ++mf)
#pragma unroll
      for (int r = 0; r < 4; ++r) mx = fmaxf(mx, s[mf][r]);
    mx = fmaxf(mx, __shfl_xor(mx, 16, 64));
    mx = fmaxf(mx, __shfl_xor(mx, 32, 64));
    // defer-max: skip O-rescale while tile max stays within THR of running m
    if (!__all(mx - m_r <= 8.0f)) {
      const float m_new = fmaxf(m_r, mx);
      const float al = exp2f(m_r - m_new);
      m_r = m_new;
      l_r *= al;
      float alr[4];
#pragma unroll
      for (int r = 0; r < 4; ++r) alr[r] = __shfl(al, quad * 4 + r, 16);
#pragma unroll
      for (int j = 0; j < 4; ++j)
#pragma unroll
        for (int r = 0; r < 4; ++r) o[j][r] *= alr[r];
    }
    float ps = 0.f;
#pragma unroll
    for (int mf = 0; mf < 4; ++mf) {
      u16x4 pk;
#pragma unroll
      for (int r = 0; r < 4; ++r) {
        const float e = exp2f(s[mf][r] - m_r);
        ps += e;
        pk[r] = f2bf(e);
      }
      *(u16x4*)&p_lds[wave][c16][mf * 16 + quad * 4] = pk;
    }
    ps += __shfl_xor(ps, 16, 64);
    ps += __shfl_xor(ps, 32, 64);
    l_r += ps;
    __threadfence_block();  // order this wave's p_lds writes before reads

    // ---- O += P @ V : D[m=q][n=d], A=P-frag, B=Vt-frag ----
    bf16x8 pf0, pf1;
    {
      const unsigned short* pw = &p_lds[wave][c16][quad * 8];
      pf0 = ld8_lds(pw);
      pf1 = ld8_lds(pw + 32);
    }
    __builtin_amdgcn_s_setprio(1);
#pragma unroll
    for (int j = 0; j < 4; ++j) {
      const unsigned short* vr = &vt_lds[j * 16 + c16][quad * 8];
      const bf16x8 v0 = ld8_lds(vr);
      const bf16x8 v1 = ld8_lds(vr + 32);
      o[j] = __builtin_amdgcn_mfma_f32_16x16x32_bf16(pf0, v0, o[j], 0, 0, 0);
      o[j] = __builtin_amdgcn_mfma_f32_16x16x32_bf16(pf1, v1, o[j], 0, 0, 0);
    }
    __builtin_amdgcn_s_setprio(0);
  };

  for (int t = 0; t < ntiles; ++t) {
    const int kb0 = t * 64;
    __syncthreads();  // all waves done reading tile t-1
    {
      const unsigned short* kp = kp0 + (size_t)kb0 * DM;
      u16x8 ka = *(const u16x8*)kp;
      u16x8 kc = *(const u16x8*)(kp + 8);
      const unsigned short* vp = vp0 + kb0;
      u16x8 va = *(const u16x8*)vp;
      u16x8 vc = *(const u16x8*)(vp + 8);
      *(u16x4*)&k_lds[srow][scol]       = lo4(ka);
      *(u16x4*)&k_lds[srow][scol + 4]   = hi4(ka);
      *(u16x4*)&k_lds[srow][scol + 8]   = lo4(kc);
      *(u16x4*)&k_lds[srow][scol + 12]  = hi4(kc);
      *(u16x4*)&vt_lds[srow][scol]      = lo4(va);
      *(u16x4*)&vt_lds[srow][scol + 4]  = hi4(va);
      *(u16x4*)&vt_lds[srow][scol + 8]  = lo4(vc);
      *(u16x4*)&vt_lds[srow][scol + 12] = hi4(vc);
    }
    __syncthreads();
    if (t < ntA_w) subtile(qfA, oA, mA, lAr, q_loA, kb0);
    if (t < ntB_w) subtile(qfB, oB, mB, lBr, q_loB, kb0);
  }

  // ---- epilogue: O/l, C-layout scatter (q = row); l via width-16 shfl ----
  auto epi = [&](f32x4 (&o)[4], float l_r, const int q_lo) {
#pragma unroll
    for (int r = 0; r < 4; ++r) {
      const int qg = q_lo + quad * 4 + r;
      const float inv = 1.0f / __shfl(l_r, quad * 4 + r, 16);
      unsigned short* orow = Ow + rkbase + (size_t)qg * DM;
#pragma unroll
      for (int j = 0; j < 4; ++j)
        orow[j * 16 + c16] = f2bf(o[j][r] * inv);
    }
  };
  epi(oA, lAr, q_loA);
  epi(oB, lBr, q_loB);
}

extern "C" void kernel_launch(void* const* d_in, const int* in_sizes, int n_in,
                              void* d_out, int out_size, void* d_ws, size_t ws_size,
                              hipStream_t stream) {
  const float* x_q  = (const float*)d_in[0];
  const float* x_kv = (const float*)d_in[1];
  const float* Wq   = (const float*)d_in[2];
  const float* Wk   = (const float*)d_in[3];
  const float* Wv   = (const float*)d_in[4];
  const float* Wo   = (const float*)d_in[5];
  float* out = (float*)d_out;

  // d_out doubles as early scratch; final GEMM reads only from ws.
  unsigned short* scr  = (unsigned short*)d_out;
  unsigned short* Sx   = scr;                          // x bf16 slot
  unsigned short* Wk_b = scr + (size_t)MROWS * DM;     // Wk|Wv|Wq contiguous
  unsigned short* Wv_b = Wk_b + (size_t)DM * DM;
  unsigned short* Wq_b = Wv_b + (size_t)DM * DM;

  unsigned short* qb   = (unsigned short*)d_ws;
  unsigned short* kb   = qb + (size_t)MROWS * DM;
  unsigned short* vtb  = kb + (size_t)MROWS * DM;      // Vt[b][h][d][t]
  unsigned short* Wo_b = vtb + (size_t)MROWS * DM;

  const int nW8 = DM * DM / 8;
  const int nX8 = MROWS * DM / 8;
  (void)Wv_b;

  // stage 1: all 4 weights + x_kv in one dispatch
  conv_stage1<<<4 * (nW8 / 256) + nX8 / 256, 256, 0, stream>>>(
      Wk, Wv, Wq, Wo, x_kv, Wk_b, Wo_b, Sx);

  // Fused K+V projection: B = [Wk_b ; Wv_b], N=2048, 1024 blocks.
  gemm128<3><<<dim3(2 * DM / 128, MROWS / 128), 256, 0, stream>>>(
      Sx, Wk_b, kb, vtb, MROWS, 2 * DM, DM);
  conv_f32_bf16<<<nX8 / 256, 256, 0, stream>>>(x_q, Sx, nX8);
  // Q projection (QSCALE folded into epilogue, MODE 4).
  gemm128<4><<<dim3(DM / 128, MROWS / 128), 256, 0, stream>>>(
      Sx, Wq_b, qb, nullptr, MROWS, DM, DM);
  attn_flash2<<<dim3(16, NH, BB), 256, 0, stream>>>(qb, kb, vtb, qb);
  gemm128<1><<<dim3(DM / 128, MROWS / 128), 256, 0, stream>>>(
      qb, Wo_b, out, nullptr, MROWS, DM, DM);
}

// Round 10
// 287.656 us; speedup vs baseline: 1.0682x; 1.0388x over previous
//
#include <hip/hip_runtime.h>
#include <stdint.h>

#define T_SEQ 2048
#define NH 16
#define HD 64
#define DM 1024
#define BB 4
#define MROWS (BB * T_SEQ)   // 8192

// Q projection is pre-scaled by 1/sqrt(HD) * log2(e) so attention scores are
// already in the log2 domain: P = exp2(s - m), alpha = exp2(m_old - m_new).
#define QSCALE 0.18033688011112042f  // 0.125 * log2(e)

typedef __attribute__((ext_vector_type(8))) __bf16 bf16x8;
typedef __attribute__((ext_vector_type(8))) unsigned short u16x8;
typedef __attribute__((ext_vector_type(4))) unsigned short u16x4;
typedef __attribute__((ext_vector_type(4))) float f32x4;

// Native cast -> compiler emits v_cvt_pk_bf16_f32 (RNE, pairs fuse).
__device__ __forceinline__ unsigned short f2bf(float f) {
  return __builtin_bit_cast(unsigned short, (__bf16)f);
}

__device__ __forceinline__ bf16x8 ld8_f32(const float* __restrict__ p) {
  f32x4 a = *(const f32x4*)p;
  f32x4 b = *(const f32x4*)(p + 4);
  u16x8 u;
#pragma unroll
  for (int i = 0; i < 4; ++i) {
    u[i]     = f2bf(a[i]);
    u[i + 4] = f2bf(b[i]);
  }
  return __builtin_bit_cast(bf16x8, u);
}

__device__ __forceinline__ bf16x8 ld8_bf(const unsigned short* p) {
  return __builtin_bit_cast(bf16x8, *(const u16x8*)p);
}

// 8-aligned LDS read as two b64s (stride-68 layouts are not 16B-aligned)
__device__ __forceinline__ bf16x8 ld8_lds(const unsigned short* p) {
  u16x4 a = *(const u16x4*)p;
  u16x4 b = *(const u16x4*)(p + 4);
  return __builtin_bit_cast(bf16x8,
      __builtin_shufflevector(a, b, 0, 1, 2, 3, 4, 5, 6, 7));
}

__device__ __forceinline__ u16x4 lo4(u16x8 v) {
  return __builtin_shufflevector(v, v, 0, 1, 2, 3);
}
__device__ __forceinline__ u16x4 hi4(u16x8 v) {
  return __builtin_shufflevector(v, v, 4, 5, 6, 7);
}

__device__ __forceinline__ void gload_lds16(const unsigned short* g,
                                            unsigned short* l) {
  __builtin_amdgcn_global_load_lds(
      (const __attribute__((address_space(1))) unsigned int*)g,
      (__attribute__((address_space(3))) unsigned int*)l, 16, 0, 0);
}

// ---------------------------------------------------------------------------
// R10: fused stage-1 conversion — 4 weights + x_kv + x_q in ONE dispatch.
// Segment select is block-uniform; all sizes are exact multiples.
// ---------------------------------------------------------------------------
__global__ __launch_bounds__(256) void conv_stage1(
    const float* __restrict__ Wk, const float* __restrict__ Wv,
    const float* __restrict__ Wq, const float* __restrict__ Wo,
    const float* __restrict__ xkv, const float* __restrict__ xq,
    unsigned short* __restrict__ Wkb012, unsigned short* __restrict__ Wob,
    unsigned short* __restrict__ Sxkv, unsigned short* __restrict__ Sxq) {
  const int bid = blockIdx.x;
  const int WSEG = (DM * DM / 8) / 256;   // 512 blocks per weight
  const int XSEG = (MROWS * DM / 8) / 256;  // 4096 blocks per activation
  if (bid < 4 * WSEG) {
    const int w = bid >> 9;
    const float* src = (w == 0) ? Wk : (w == 1) ? Wv : (w == 2) ? Wq : Wo;
    unsigned short* dst = (w < 3) ? Wkb012 + (size_t)w * DM * DM : Wob;
    const int i = (bid & (WSEG - 1)) * 256 + threadIdx.x;
    *(u16x8*)(dst + (size_t)i * 8) =
        __builtin_bit_cast(u16x8, ld8_f32(src + (size_t)i * 8));
  } else if (bid < 4 * WSEG + XSEG) {
    const int i = (bid - 4 * WSEG) * 256 + threadIdx.x;
    *(u16x8*)(Sxkv + (size_t)i * 8) =
        __builtin_bit_cast(u16x8, ld8_f32(xkv + (size_t)i * 8));
  } else {
    const int i = (bid - 4 * WSEG - XSEG) * 256 + threadIdx.x;
    *(u16x8*)(Sxq + (size_t)i * 8) =
        __builtin_bit_cast(u16x8, ld8_f32(xq + (size_t)i * 8));
  }
}

// ---------------------------------------------------------------------------
// bf16 GEMM (proven R7 structure: 128x128 tile, BK=64 via two BK=32 planes,
// 2-phase double-buffered gload_lds staging, XCD remap on contiguous
// m-panels).
// MODE 1: f32 row-major out (O projection).
// MODE 5 (R10): MEGA-QKV. B = [Wk|Wv|Wq] (3072x1024 contiguous), N=3072.
//   n-tile selects A (x_kv for n<2048, x_q for n>=2048) and epilogue:
//   n<1024 -> K bf16 row-major (Cv); n<2048 -> Vt[b][h][d][t] (Cv2);
//   else -> Q bf16 row-major * QSCALE (Cv3). All branches block-uniform.
//   Collapses {KV GEMM, x_q conv, Q GEMM} into one 1536-block dispatch:
//   removes a serialized conv + 2 launch gaps; Q blocks backfill KV tail.
// ---------------------------------------------------------------------------
template <int MODE>
__global__ __launch_bounds__(256) void gemm128(
    const unsigned short* __restrict__ A, const unsigned short* __restrict__ A2,
    const unsigned short* __restrict__ B, void* __restrict__ Cv,
    void* __restrict__ Cv2, void* __restrict__ Cv3, int M, int N, int K) {
  __shared__ __align__(16) unsigned short As[2][2][128 * 32];
  __shared__ __align__(16) unsigned short Bs[2][2][128 * 32];

  const int t = threadIdx.x;
  const int lane = t & 63, wave = t >> 6;
  const int lin = (int)(blockIdx.x + gridDim.x * blockIdx.y);
  const int nx = N >> 7;                       // n-tiles
  const int mpx = (M >> 7) >> 3;               // m-panels per XCD
  const int xcd = lin & 7, slot = lin >> 3;
  const int m0 = (xcd * mpx + slot / nx) * 128;
  const int n0 = (slot % nx) * 128;

  const unsigned short* Ause = A;
  if constexpr (MODE == 5) {
    if (n0 >= 2 * DM) Ause = A2;   // Q-tiles read x_q (block-uniform)
  }

  const int srow = t >> 2;
  const int scol = (t & 3) * 8;
  const unsigned short* ga0 = Ause + (size_t)(m0 + srow) * K + scol;
  const unsigned short* ga1 = Ause + (size_t)(m0 + 64 + srow) * K + scol;
  const unsigned short* gb0 = B + (size_t)(n0 + srow) * K + scol;
  const unsigned short* gb1 = B + (size_t)(n0 + 64 + srow) * K + scol;
  const int lo0 = (wave * 16) * 32, lo1 = (64 + wave * 16) * 32;

  const int mw = (wave >> 1) * 64, nw = (wave & 1) * 64;
  const int fr = lane & 15, fq = (lane >> 4) * 8;

  f32x4 acc[4][4];
#pragma unroll
  for (int i = 0; i < 4; ++i)
#pragma unroll
    for (int j = 0; j < 4; ++j) acc[i][j] = (f32x4){0.f, 0.f, 0.f, 0.f};

  auto stage = [&](int buf, int k0) {
    gload_lds16(ga0 + k0,      &As[buf][0][lo0]);
    gload_lds16(ga1 + k0,      &As[buf][0][lo1]);
    gload_lds16(gb0 + k0,      &Bs[buf][0][lo0]);
    gload_lds16(gb1 + k0,      &Bs[buf][0][lo1]);
    gload_lds16(ga0 + k0 + 32, &As[buf][1][lo0]);
    gload_lds16(ga1 + k0 + 32, &As[buf][1][lo1]);
    gload_lds16(gb0 + k0 + 32, &Bs[buf][1][lo0]);
    gload_lds16(gb1 + k0 + 32, &Bs[buf][1][lo1]);
  };

  // prologue: stage tile 0 (latency exposed once)
  stage(0, 0);
  __syncthreads();

  const int NT = K >> 6;   // 16
  int cur = 0;
  for (int kt = 0; kt < NT; ++kt) {
    if (kt + 1 < NT) stage(cur ^ 1, (kt + 1) << 6);  // overlaps compute below
#pragma unroll
    for (int ks = 0; ks < 2; ++ks) {
      bf16x8 af[4], bfr[4];
#pragma unroll
      for (int i = 0; i < 4; ++i)
        af[i] = ld8_bf(&As[cur][ks][(mw + i * 16 + fr) * 32 + fq]);
#pragma unroll
      for (int j = 0; j < 4; ++j)
        bfr[j] = ld8_bf(&Bs[cur][ks][(nw + j * 16 + fr) * 32 + fq]);
#pragma unroll
      for (int i = 0; i < 4; ++i)
#pragma unroll
        for (int j = 0; j < 4; ++j)
          acc[i][j] = __builtin_amdgcn_mfma_f32_16x16x32_bf16(
              af[i], bfr[j], acc[i][j], 0, 0, 0);
    }
    __syncthreads();  // drains vmcnt(0): next buf ready; cur safe to overwrite
    cur ^= 1;
  }

  const int orow = (lane >> 4) * 4, ocol = lane & 15;
#pragma unroll
  for (int i = 0; i < 4; ++i)
#pragma unroll
    for (int j = 0; j < 4; ++j) {
      const int mb = m0 + mw + i * 16 + orow;
      const int n = n0 + nw + j * 16 + ocol;
      if constexpr (MODE == 5) {
        if (n0 < DM) {            // K path: bf16 row-major, stride DM
#pragma unroll
          for (int r = 0; r < 4; ++r)
            ((unsigned short*)Cv)[(size_t)(mb + r) * DM + n] =
                f2bf(acc[i][j][r]);
        } else if (n0 < 2 * DM) {  // V path: Vt[b][h][d][t]
          const int nv = n - DM;
          u16x4 pk;
#pragma unroll
          for (int r = 0; r < 4; ++r) pk[r] = f2bf(acc[i][j][r]);
          unsigned short* dst = (unsigned short*)Cv2 +
              ((size_t)((mb >> 11) * NH + (nv >> 6)) * HD + (nv & 63)) *
                  T_SEQ +
              (mb & 2047);
          *(u16x4*)dst = pk;
        } else {                  // Q path: bf16 row-major * QSCALE
          const int nq = n - 2 * DM;
#pragma unroll
          for (int r = 0; r < 4; ++r)
            ((unsigned short*)Cv3)[(size_t)(mb + r) * DM + nq] =
                f2bf(acc[i][j][r] * QSCALE);
        }
      } else {                    // MODE 1: f32 row-major
#pragma unroll
        for (int r = 0; r < 4; ++r)
          ((float*)Cv)[(size_t)(mb + r) * N + n] = acc[i][j][r];
      }
    }
}

// ---------------------------------------------------------------------------
// MFMA flash attention v2 (causal) — R7 version restored verbatim (best
// measured: 88-90 µs; R9's occupancy-doubled variant was slower — attn is
// VALU-chain-bound, not wave-starved). Paired q-tiles {15-pi, pi}; S^T =
// K @ Q^T; scores pre-scaled to log2 domain; defer-max THR=8; alpha/l via
// width-16 shuffles; K/V LDS double-buffer, 1 barrier/tile.
// ---------------------------------------------------------------------------
#define ASTR 68

__global__ __launch_bounds__(256, 2) void attn_flash2(
    const unsigned short* Qw, const unsigned short* __restrict__ Kw,
    const unsigned short* __restrict__ Vt, unsigned short* Ow) {
  __shared__ __align__(16) unsigned short k_lds[2][64][ASTR];
  __shared__ __align__(16) unsigned short vt_lds[2][64][ASTR];
  __shared__ __align__(16) unsigned short p_lds[4][32][ASTR];

  const int tid = threadIdx.x, lane = tid & 63, wave = tid >> 6;
  const int c16 = lane & 15, quad = lane >> 4;
  const int b = blockIdx.z, h = blockIdx.y;
  const int pi = blockIdx.x;            // pair index 0..7
  const int qb0A = (15 - pi) * 128;     // heavy
  const int qb0B = pi * 128;            // light
  const size_t rkbase = (size_t)b * T_SEQ * DM + (size_t)h * HD;
  const size_t vtbase = (size_t)(b * NH + h) * HD * T_SEQ;

  const int q_loA = qb0A + wave * 32;
  const int q_loB = qb0B + wave * 32;

  bf16x8 qfA[2][2], qfB[2][2];
#pragma unroll
  for (int nf = 0; nf < 2; ++nf) {
    const unsigned short* qpA =
        Qw + rkbase + (size_t)(q_loA + nf * 16 + c16) * DM + quad * 8;
    qfA[nf][0] = ld8_bf(qpA);
    qfA[nf][1] = ld8_bf(qpA + 32);
    const unsigned short* qpB =
        Qw + rkbase + (size_t)(q_loB + nf * 16 + c16) * DM + quad * 8;
    qfB[nf][0] = ld8_bf(qpB);
    qfB[nf][1] = ld8_bf(qpB + 32);
  }

  f32x4 oA[2][4], oB[2][4];
#pragma unroll
  for (int nf = 0; nf < 2; ++nf)
#pragma unroll
    for (int j = 0; j < 4; ++j) {
      oA[nf][j] = (f32x4){0.f, 0.f, 0.f, 0.f};
      oB[nf][j] = (f32x4){0.f, 0.f, 0.f, 0.f};
    }
  float mA[2] = {-3.0e38f, -3.0e38f}, lA[2] = {0.f, 0.f};
  float mB[2] = {-3.0e38f, -3.0e38f}, lB[2] = {0.f, 0.f};

  const int srow = tid >> 2;
  const int scol = (tid & 3) * 16;
  const int ntiles = (qb0A + 191) >> 6;
  const int ntA_w = (q_loA + 95) >> 6;
  const int ntB_w = (q_loB + 95) >> 6;

  const unsigned short* kp0 = Kw + rkbase + (size_t)srow * DM + scol;
  const unsigned short* vp0 = Vt + vtbase + (size_t)srow * T_SEQ + scol;

  auto subtile = [&](const bf16x8 (&qf)[2][2], f32x4 (&o)[2][4],
                     float (&m_r)[2], float (&l_r)[2], const int q_lo,
                     const int kb0, const int bi) {
    f32x4 s[4][2];
    __builtin_amdgcn_s_setprio(1);
#pragma unroll
    for (int mf = 0; mf < 4; ++mf) {
      const unsigned short* kr = &k_lds[bi][mf * 16 + c16][quad * 8];
      const bf16x8 k0 = ld8_lds(kr);
      const bf16x8 k1 = ld8_lds(kr + 32);
#pragma unroll
      for (int nf = 0; nf < 2; ++nf) {
        f32x4 a = {0.f, 0.f, 0.f, 0.f};
        a = __builtin_amdgcn_mfma_f32_16x16x32_bf16(k0, qf[nf][0], a, 0, 0, 0);
        a = __builtin_amdgcn_mfma_f32_16x16x32_bf16(k1, qf[nf][1], a, 0, 0, 0);
        s[mf][nf] = a;
      }
    }
    __builtin_amdgcn_s_setprio(0);
    if (kb0 + 63 > q_lo) {
#pragma unroll
      for (int mf = 0; mf < 4; ++mf) {
        const int key0 = kb0 + mf * 16 + quad * 4;
#pragma unroll
        for (int nf = 0; nf < 2; ++nf) {
          const int qg = q_lo + nf * 16 + c16;
#pragma unroll
          for (int r = 0; r < 4; ++r)
            if (key0 + r > qg) s[mf][nf][r] = -3.0e38f;
        }
      }
    }

#pragma unroll
    for (int nf = 0; nf < 2; ++nf) {
      float mx = -3.0e38f;
#pragma unroll
      for (int mf = 0; mf < 4; ++mf)
#pragma unroll
        for (int r = 0; r < 4; ++r) mx = fmaxf(mx, s[mf][nf][r]);
      mx = fmaxf(mx, __shfl_xor(mx, 16, 64));
      mx = fmaxf(mx, __shfl_xor(mx, 32, 64));
      if (!__all(mx - m_r[nf] <= 8.0f)) {
        const float m_new = fmaxf(m_r[nf], mx);
        const float al = exp2f(m_r[nf] - m_new);
        m_r[nf] = m_new;
        l_r[nf] *= al;
        float alr[4];
#pragma unroll
        for (int r = 0; r < 4; ++r) alr[r] = __shfl(al, quad * 4 + r, 16);
#pragma unroll
        for (int j = 0; j < 4; ++j)
#pragma unroll
          for (int r = 0; r < 4; ++r) o[nf][j][r] *= alr[r];
      }
      float ps = 0.f;
#pragma unroll
      for (int mf = 0; mf < 4; ++mf) {
        u16x4 pk;
#pragma unroll
        for (int r = 0; r < 4; ++r) {
          const float e = exp2f(s[mf][nf][r] - m_r[nf]);
          ps += e;
          pk[r] = f2bf(e);
        }
        *(u16x4*)&p_lds[wave][nf * 16 + c16][mf * 16 + quad * 4] = pk;
      }
      ps += __shfl_xor(ps, 16, 64);
      ps += __shfl_xor(ps, 32, 64);
      l_r[nf] += ps;
    }
    __threadfence_block();

    bf16x8 pf[2][2];
#pragma unroll
    for (int nf = 0; nf < 2; ++nf) {
      const unsigned short* pw = &p_lds[wave][nf * 16 + c16][quad * 8];
      pf[nf][0] = ld8_lds(pw);
      pf[nf][1] = ld8_lds(pw + 32);
    }
    __builtin_amdgcn_s_setprio(1);
#pragma unroll
    for (int j = 0; j < 4; ++j) {
      const unsigned short* vr = &vt_lds[bi][j * 16 + c16][quad * 8];
      const bf16x8 v0 = ld8_lds(vr);
      const bf16x8 v1 = ld8_lds(vr + 32);
#pragma unroll
      for (int nf = 0; nf < 2; ++nf) {
        o[nf][j] = __builtin_amdgcn_mfma_f32_16x16x32_bf16(pf[nf][0], v0,
                                                           o[nf][j], 0, 0, 0);
        o[nf][j] = __builtin_amdgcn_mfma_f32_16x16x32_bf16(pf[nf][1], v1,
                                                           o[nf][j], 0, 0, 0);
      }
    }
    __builtin_amdgcn_s_setprio(0);
  };

  {
    u16x8 ka = *(const u16x8*)kp0;
    u16x8 kc = *(const u16x8*)(kp0 + 8);
    u16x8 va = *(const u16x8*)vp0;
    u16x8 vc = *(const u16x8*)(vp0 + 8);
    *(u16x4*)&k_lds[0][srow][scol]       = lo4(ka);
    *(u16x4*)&k_lds[0][srow][scol + 4]   = hi4(ka);
    *(u16x4*)&k_lds[0][srow][scol + 8]   = lo4(kc);
    *(u16x4*)&k_lds[0][srow][scol + 12]  = hi4(kc);
    *(u16x4*)&vt_lds[0][srow][scol]      = lo4(va);
    *(u16x4*)&vt_lds[0][srow][scol + 4]  = hi4(va);
    *(u16x4*)&vt_lds[0][srow][scol + 8]  = lo4(vc);
    *(u16x4*)&vt_lds[0][srow][scol + 12] = hi4(vc);
  }
  __syncthreads();

  int cur = 0;
  for (int t = 0; t < ntiles; ++t) {
    const int kb0 = t * 64;
    const bool pf = (t + 1 < ntiles);
    u16x8 ka, kc, va, vc;
    if (pf) {
      const unsigned short* kp = kp0 + (size_t)(kb0 + 64) * DM;
      ka = *(const u16x8*)kp;
      kc = *(const u16x8*)(kp + 8);
      const unsigned short* vp = vp0 + (kb0 + 64);
      va = *(const u16x8*)vp;
      vc = *(const u16x8*)(vp + 8);
    }
    if (t < ntA_w) subtile(qfA, oA, mA, lA, q_loA, kb0, cur);
    if (t < ntB_w) subtile(qfB, oB, mB, lB, q_loB, kb0, cur);
    if (pf) {
      const int nb = cur ^ 1;
      *(u16x4*)&k_lds[nb][srow][scol]       = lo4(ka);
      *(u16x4*)&k_lds[nb][srow][scol + 4]   = hi4(ka);
      *(u16x4*)&k_lds[nb][srow][scol + 8]   = lo4(kc);
      *(u16x4*)&k_lds[nb][srow][scol + 12]  = hi4(kc);
      *(u16x4*)&vt_lds[nb][srow][scol]      = lo4(va);
      *(u16x4*)&vt_lds[nb][srow][scol + 4]  = hi4(va);
      *(u16x4*)&vt_lds[nb][srow][scol + 8]  = lo4(vc);
      *(u16x4*)&vt_lds[nb][srow][scol + 12] = hi4(vc);
      __syncthreads();
      cur = nb;
    }
  }

  auto epi = [&](f32x4 (&o)[2][4], float (&l_r)[2], const int q_lo) {
#pragma unroll
    for (int nf = 0; nf < 2; ++nf)
#pragma unroll
      for (int r = 0; r < 4; ++r) {
        const int qg = q_lo + nf * 16 + quad * 4 + r;
        const float inv = 1.0f / __shfl(l_r[nf], quad * 4 + r, 16);
        unsigned short* orow = Ow + rkbase + (size_t)qg * DM;
#pragma unroll
        for (int j = 0; j < 4; ++j)
          orow[j * 16 + c16] = f2bf(o[nf][j][r] * inv);
      }
  };
  epi(oA, lA, q_loA);
  epi(oB, lB, q_loB);
}

extern "C" void kernel_launch(void* const* d_in, const int* in_sizes, int n_in,
                              void* d_out, int out_size, void* d_ws, size_t ws_size,
                              hipStream_t stream) {
  const float* x_q  = (const float*)d_in[0];
  const float* x_kv = (const float*)d_in[1];
  const float* Wq   = (const float*)d_in[2];
  const float* Wk   = (const float*)d_in[3];
  const float* Wv   = (const float*)d_in[4];
  const float* Wo   = (const float*)d_in[5];
  float* out = (float*)d_out;

  // d_out (32MB) = Sx_kv | Sx_q (exact fit); fully overwritten by final GEMM.
  unsigned short* Sxkv = (unsigned short*)d_out;
  unsigned short* Sxq  = Sxkv + (size_t)MROWS * DM;

  // ws: qb | kb | vtb | Wk_b|Wv_b|Wq_b (contiguous 3072x1024) | Wo_b = 56MB.
  unsigned short* qb   = (unsigned short*)d_ws;
  unsigned short* kb   = qb + (size_t)MROWS * DM;
  unsigned short* vtb  = kb + (size_t)MROWS * DM;      // Vt[b][h][d][t]
  unsigned short* Wk_b = vtb + (size_t)MROWS * DM;
  unsigned short* Wo_b = Wk_b + (size_t)3 * DM * DM;

  const int nW8 = DM * DM / 8;
  const int nX8 = MROWS * DM / 8;

  // stage 1: 4 weights + x_kv + x_q in one dispatch (10240 blocks)
  conv_stage1<<<4 * (nW8 / 256) + 2 * (nX8 / 256), 256, 0, stream>>>(
      Wk, Wv, Wq, Wo, x_kv, x_q, Wk_b, Wo_b, Sxkv, Sxq);

  // Mega-QKV: one dispatch, N=3072 over [Wk|Wv|Wq]; 1536 blocks.
  gemm128<5><<<dim3(3 * DM / 128, MROWS / 128), 256, 0, stream>>>(
      Sxkv, Sxq, Wk_b, kb, vtb, qb, MROWS, 3 * DM, DM);
  attn_flash2<<<dim3(8, NH, BB), 256, 0, stream>>>(qb, kb, vtb, qb);
  gemm128<1><<<dim3(DM / 128, MROWS / 128), 256, 0, stream>>>(
      qb, nullptr, Wo_b, out, nullptr, nullptr, MROWS, DM, DM);
}